// Round 2
// baseline (841.559 us; speedup 1.0000x reference)
//
#include <hip/hip_runtime.h>
#include <hip/hip_bf16.h>

#define N_NODES 50000
#define N_EDGES 800000
#define F_IN 256
#define HID 64
#define HEADS 4
#define NEG 0.2f
#define LN_EPS 1e-5f

__device__ __forceinline__ float wave_sum(float v) {
    #pragma unroll
    for (int o = 32; o > 0; o >>= 1) v += __shfl_xor(v, o, 64);
    return v;
}
__device__ __forceinline__ float wave_max(float v) {
    #pragma unroll
    for (int o = 32; o > 0; o >>= 1) v = fmaxf(v, __shfl_xor(v, o, 64));
    return v;
}
__device__ __forceinline__ float leaky(float x) { return x > 0.0f ? x : NEG * x; }

// ---------------- CSR build ----------------
__global__ void count_kernel(const int* __restrict__ dst, int* __restrict__ deg,
                             int E, int Etot) {
    int e = blockIdx.x * blockDim.x + threadIdx.x;
    if (e >= Etot) return;
    int d = (e < E) ? dst[e] : (e - E);   // tail = self loops
    atomicAdd(&deg[d], 1);
}

__global__ void scan_kernel(const int* __restrict__ deg, int* __restrict__ row_ptr, int N) {
    __shared__ int part[1024];
    int t = threadIdx.x;
    int chunk = (N + 1023) / 1024;
    int base = t * chunk;
    int local = 0;
    for (int j = 0; j < chunk; ++j) {
        int idx = base + j;
        if (idx < N) local += deg[idx];
    }
    part[t] = local;
    __syncthreads();
    for (int off = 1; off < 1024; off <<= 1) {
        int v = 0;
        if (t >= off) v = part[t - off];
        __syncthreads();
        part[t] += v;
        __syncthreads();
    }
    int run = (t == 0) ? 0 : part[t - 1];
    for (int j = 0; j < chunk; ++j) {
        int idx = base + j;
        if (idx < N) { run += deg[idx]; row_ptr[idx + 1] = run; }
    }
    if (t == 0) row_ptr[0] = 0;
}

__global__ void scatter_kernel(const int* __restrict__ src, const int* __restrict__ dst,
                               const int* __restrict__ row_ptr, int* __restrict__ fill,
                               int* __restrict__ col, int E, int Etot) {
    int e = blockIdx.x * blockDim.x + threadIdx.x;
    if (e >= Etot) return;
    int s, d;
    if (e < E) { s = src[e]; d = dst[e]; }
    else       { s = d = e - E; }
    int pos = atomicAdd(&fill[d], 1);
    col[row_ptr[d] + pos] = s;
}

// ---------------- fp32 tiled GEMM:  C[m,n] = sum_k A[m,k]*B[n,k] (+bias[n]) ----------------
// A: [M,K] row-major, B: [Nc,K] row-major (i.e. computes A @ B^T). K % 16 == 0.
__global__ void gemm_nt(const float* __restrict__ A, const float* __restrict__ B,
                        const float* __restrict__ bias, float* __restrict__ C,
                        int M, int Nc, int K, int addBias) {
    __shared__ float As[16][64];
    __shared__ float Bs[16][64];
    int tid = threadIdx.x;           // 256 threads
    int row0 = blockIdx.y * 64;
    int col0 = blockIdx.x * 64;
    int tr = tid / 16;               // 0..15
    int tc = tid % 16;               // 0..15
    float acc[4][4] = {};
    int lm = tid / 4;                // 0..63
    int lk = (tid % 4) * 4;          // 0,4,8,12

    for (int k0 = 0; k0 < K; k0 += 16) {
        {
            int gr = row0 + lm;
            float4 v = make_float4(0.f, 0.f, 0.f, 0.f);
            if (gr < M) v = *(const float4*)(A + (size_t)gr * K + k0 + lk);
            As[lk + 0][lm] = v.x; As[lk + 1][lm] = v.y;
            As[lk + 2][lm] = v.z; As[lk + 3][lm] = v.w;
        }
        {
            int gc = col0 + lm;
            float4 v = make_float4(0.f, 0.f, 0.f, 0.f);
            if (gc < Nc) v = *(const float4*)(B + (size_t)gc * K + k0 + lk);
            Bs[lk + 0][lm] = v.x; Bs[lk + 1][lm] = v.y;
            Bs[lk + 2][lm] = v.z; Bs[lk + 3][lm] = v.w;
        }
        __syncthreads();
        #pragma unroll
        for (int k = 0; k < 16; ++k) {
            float4 a4 = *(const float4*)&As[k][tr * 4];
            float4 b4 = *(const float4*)&Bs[k][tc * 4];
            float a[4] = {a4.x, a4.y, a4.z, a4.w};
            float b[4] = {b4.x, b4.y, b4.z, b4.w};
            #pragma unroll
            for (int i = 0; i < 4; ++i)
                #pragma unroll
                for (int j = 0; j < 4; ++j)
                    acc[i][j] += a[i] * b[j];
        }
        __syncthreads();
    }
    #pragma unroll
    for (int i = 0; i < 4; ++i) {
        int gr = row0 + tr * 4 + i;
        if (gr >= M) continue;
        #pragma unroll
        for (int j = 0; j < 4; ++j) {
            int gc = col0 + tc * 4 + j;
            if (gc < Nc) {
                float v = acc[i][j];
                if (addBias) v += bias[gc];
                C[(size_t)gr * Nc + gc] = v;
            }
        }
    }
}

// ---------------- attention coefficients: a_src[n,h] = <h[n,h,:], att_src[h,:]> ----------------
__global__ void att_coef(const float* __restrict__ h, const float* __restrict__ att_src,
                         const float* __restrict__ att_dst, float* __restrict__ a_src,
                         float* __restrict__ a_dst, int N, int H) {
    int wave = threadIdx.x >> 6, lane = threadIdx.x & 63;
    int node = blockIdx.x * (blockDim.x >> 6) + wave;
    if (node >= N) return;
    for (int hh = 0; hh < H; ++hh) {
        float v = h[(size_t)node * H * 64 + hh * 64 + lane];
        float s1 = wave_sum(v * att_src[hh * 64 + lane]);
        float s2 = wave_sum(v * att_dst[hh * 64 + lane]);
        if (lane == 0) { a_src[node * H + hh] = s1; a_dst[node * H + hh] = s2; }
    }
}

// ---------------- GAT aggregation (gather by dst over CSR): block=node, wave=head ----------------
__global__ void gat_agg(const float* __restrict__ h, const float* __restrict__ a_src,
                        const float* __restrict__ a_dst, const int* __restrict__ row_ptr,
                        const int* __restrict__ col, const float* __restrict__ bias,
                        float* __restrict__ out, int N, int H, int leaky_out) {
    int i = blockIdx.x;
    int w = threadIdx.x >> 6, lane = threadIdx.x & 63;
    int start = row_ptr[i], end = row_ptr[i + 1];
    float ad = a_dst[i * H + w];

    float m = -1e30f;
    for (int j = start + lane; j < end; j += 64) {
        int s = col[j];
        m = fmaxf(m, leaky(a_src[s * H + w] + ad));
    }
    m = wave_max(m);

    float ssum = 0.0f;
    for (int j = start + lane; j < end; j += 64) {
        int s = col[j];
        ssum += __expf(leaky(a_src[s * H + w] + ad) - m);
    }
    ssum = wave_sum(ssum);
    float inv = 1.0f / ssum;

    float acc = 0.0f;
    for (int j = start; j < end; ++j) {
        int s = col[j];
        float alpha = __expf(leaky(a_src[s * H + w] + ad) - m) * inv;
        acc += alpha * h[(size_t)s * (H * 64) + w * 64 + lane];
    }
    float v = acc + bias[w * 64 + lane];
    if (leaky_out) v = leaky(v);
    out[(size_t)i * (H * 64) + w * 64 + lane] = v;
}

// ---------------- leaky + LayerNorm + residual-add (in place on lin buffer) ----------------
__global__ void ln_res(const float* __restrict__ o2, float* __restrict__ lin,
                       const float* __restrict__ gamma, const float* __restrict__ beta, int N) {
    int wave = threadIdx.x >> 6, lane = threadIdx.x & 63;
    int i = blockIdx.x * (blockDim.x >> 6) + wave;
    if (i >= N) return;
    float x = o2[(size_t)i * 64 + lane];          // already leaky'd in gat_agg epilogue
    float mu = wave_sum(x) * (1.0f / 64.0f);
    float d = x - mu;
    float var = wave_sum(d * d) * (1.0f / 64.0f);
    float xn = d * rsqrtf(var + LN_EPS) * gamma[lane] + beta[lane];
    lin[(size_t)i * 64 + lane] += xn;
}

// ---------------- GRU gates + FC head ----------------
__global__ void gru_fc(const float* __restrict__ gi, const float* __restrict__ b_hh,
                       const float* __restrict__ fc_w, const float* __restrict__ fc_b,
                       float* __restrict__ outp, int N) {
    int wave = threadIdx.x >> 6, lane = threadIdx.x & 63;
    int i = blockIdx.x * (blockDim.x >> 6) + wave;
    if (i >= N) return;
    const float* g = gi + (size_t)i * 192;
    float i_r = g[lane], i_z = g[64 + lane], i_n = g[128 + lane];
    float r = 1.0f / (1.0f + __expf(-(i_r + b_hh[lane])));
    float z = 1.0f / (1.0f + __expf(-(i_z + b_hh[64 + lane])));
    float ng = tanhf(i_n + r * b_hh[128 + lane]);
    float hy = (1.0f - z) * ng;
    #pragma unroll
    for (int k = 0; k < 3; ++k) {
        float s = wave_sum(hy * fc_w[k * 64 + lane]);
        if (lane == 0) outp[(size_t)i * 3 + k] = s + fc_b[k];
    }
}

extern "C" void kernel_launch(void* const* d_in, const int* in_sizes, int n_in,
                              void* d_out, int out_size, void* d_ws, size_t ws_size,
                              hipStream_t stream) {
    const float* x        = (const float*)d_in[0];
    const int*   ei       = (const int*)d_in[1];
    const float* W1       = (const float*)d_in[2];
    const float* att_src1 = (const float*)d_in[3];
    const float* att_dst1 = (const float*)d_in[4];
    const float* b1       = (const float*)d_in[5];
    const float* W2       = (const float*)d_in[6];
    const float* att_src2 = (const float*)d_in[7];
    const float* att_dst2 = (const float*)d_in[8];
    const float* b2       = (const float*)d_in[9];
    const float* lin_w    = (const float*)d_in[10];
    const float* lin_b    = (const float*)d_in[11];
    const float* gamma    = (const float*)d_in[12];
    const float* beta     = (const float*)d_in[13];
    const float* w_ih     = (const float*)d_in[14];
    // d_in[15] = w_hh (unused: h0 == 0)
    const float* b_ih     = (const float*)d_in[16];
    const float* b_hh     = (const float*)d_in[17];
    const float* fc_w     = (const float*)d_in[18];
    const float* fc_b     = (const float*)d_in[19];
    float* out = (float*)d_out;

    const int N = N_NODES, E = N_EDGES;
    const int Etot = E + N;
    char* ws = (char*)d_ws;

    // bump allocator (256B aligned)
    size_t off = 0;
    auto alloc = [&](size_t bytes) {
        size_t o = off;
        off = (off + bytes + 255) & ~(size_t)255;
        return o;
    };
    int*   row_ptr = (int*)(ws + alloc((size_t)(N + 1) * 4));
    int*   col     = (int*)(ws + alloc((size_t)Etot * 4));
    int*   deg     = (int*)(ws + alloc((size_t)N * 4));
    int*   fill    = (int*)(ws + alloc((size_t)N * 4));
    float* a_src1b = (float*)(ws + alloc((size_t)N * HEADS * 4));
    float* a_dst1b = (float*)(ws + alloc((size_t)N * HEADS * 4));
    float* a_src2b = (float*)(ws + alloc((size_t)N * 4));
    float* a_dst2b = (float*)(ws + alloc((size_t)N * 4));
    float* h1      = (float*)(ws + alloc((size_t)N * 256 * 4));   // region A (51.2MB)
    float* o1      = (float*)(ws + alloc((size_t)N * 256 * 4));   // region B (51.2MB)
    // region-A aliases (valid only AFTER h1's [N,256] content is dead, i.e. after gat_agg1):
    float* h2  = h1;                                              // [N,64]  (12.8MB)
    float* o2  = (float*)((char*)h1 + (size_t)16 * 1024 * 1024);  // [N,64]  at +16MB
    float* lin = (float*)((char*)h1 + (size_t)32 * 1024 * 1024);  // [N,64]  at +32MB
    // region-B alias (valid after gemm2 consumed o1):
    float* gi  = o1;                                              // [N,192] (38.4MB)

    hipMemsetAsync(deg, 0, (size_t)N * 4, stream);
    hipMemsetAsync(fill, 0, (size_t)N * 4, stream);

    // ---- CSR build (shared by both GAT layers) ----
    count_kernel<<<(Etot + 255) / 256, 256, 0, stream>>>(ei + E, deg, E, Etot);
    scan_kernel<<<1, 1024, 0, stream>>>(deg, row_ptr, N);
    scatter_kernel<<<(Etot + 255) / 256, 256, 0, stream>>>(ei, ei + E, row_ptr, fill, col, E, Etot);

    // ---- GAT layer 1 ----
    dim3 g1(4, (N + 63) / 64);
    gemm_nt<<<g1, 256, 0, stream>>>(x, W1, nullptr, h1, N, 256, 256, 0);
    att_coef<<<(N + 3) / 4, 256, 0, stream>>>(h1, att_src1, att_dst1, a_src1b, a_dst1b, N, HEADS);
    gat_agg<<<N, 256, 0, stream>>>(h1, a_src1b, a_dst1b, row_ptr, col, b1, o1, N, HEADS, 1);

    // ---- lin residual projection (reads only x; MUST run after gat_agg1 because
    //      lin lives inside region A which gemm1/h1 occupies until then) ----
    dim3 gLin(1, (N + 63) / 64);
    gemm_nt<<<gLin, 256, 0, stream>>>(x, lin_w, lin_b, lin, N, 64, 256, 1);

    // ---- GAT layer 2 ----
    dim3 g2(1, (N + 63) / 64);
    gemm_nt<<<g2, 256, 0, stream>>>(o1, W2, nullptr, h2, N, 64, 256, 0);
    att_coef<<<(N + 3) / 4, 256, 0, stream>>>(h2, att_src2, att_dst2, a_src2b, a_dst2b, N, 1);
    gat_agg<<<N, 64, 0, stream>>>(h2, a_src2b, a_dst2b, row_ptr, col, b2, o2, N, 1, 1);

    // ---- LayerNorm + residual ----
    ln_res<<<(N + 3) / 4, 256, 0, stream>>>(o2, lin, gamma, beta, N);

    // ---- GRU input GEMM: gi = hres @ w_ih^T + b_ih ----
    dim3 g3(3, (N + 63) / 64);
    gemm_nt<<<g3, 256, 0, stream>>>(lin, w_ih, b_ih, gi, N, 192, 64, 1);

    // ---- GRU gates + FC head ----
    gru_fc<<<(N + 3) / 4, 256, 0, stream>>>(gi, b_hh, fc_w, fc_b, out, N);
}

// Round 3
// 790.370 us; speedup vs baseline: 1.0648x; 1.0648x over previous
//
#include <hip/hip_runtime.h>
#include <hip/hip_bf16.h>

#define N_NODES 50000
#define N_EDGES 800000
#define F_IN 256
#define HID 64
#define HEADS 4
#define NEG 0.2f
#define LN_EPS 1e-5f

__device__ __forceinline__ float wave_sum(float v) {
    #pragma unroll
    for (int o = 32; o > 0; o >>= 1) v += __shfl_xor(v, o, 64);
    return v;
}
__device__ __forceinline__ float wave_max(float v) {
    #pragma unroll
    for (int o = 32; o > 0; o >>= 1) v = fmaxf(v, __shfl_xor(v, o, 64));
    return v;
}
__device__ __forceinline__ float leaky(float x) { return x > 0.0f ? x : NEG * x; }

// ---------------- CSR build ----------------
__global__ void count_kernel(const int* __restrict__ dst, int* __restrict__ deg,
                             int E, int Etot) {
    int e = blockIdx.x * blockDim.x + threadIdx.x;
    if (e >= Etot) return;
    int d = (e < E) ? dst[e] : (e - E);   // tail = self loops
    atomicAdd(&deg[d], 1);
}

__global__ void scan_kernel(const int* __restrict__ deg, int* __restrict__ row_ptr, int N) {
    __shared__ int part[1024];
    int t = threadIdx.x;
    int chunk = (N + 1023) / 1024;
    int base = t * chunk;
    int local = 0;
    for (int j = 0; j < chunk; ++j) {
        int idx = base + j;
        if (idx < N) local += deg[idx];
    }
    part[t] = local;
    __syncthreads();
    for (int off = 1; off < 1024; off <<= 1) {
        int v = 0;
        if (t >= off) v = part[t - off];
        __syncthreads();
        part[t] += v;
        __syncthreads();
    }
    int run = (t == 0) ? 0 : part[t - 1];
    for (int j = 0; j < chunk; ++j) {
        int idx = base + j;
        if (idx < N) { run += deg[idx]; row_ptr[idx + 1] = run; }
    }
    if (t == 0) row_ptr[0] = 0;
}

__global__ void scatter_kernel(const int* __restrict__ src, const int* __restrict__ dst,
                               const int* __restrict__ row_ptr, int* __restrict__ fill,
                               int* __restrict__ col, int E, int Etot) {
    int e = blockIdx.x * blockDim.x + threadIdx.x;
    if (e >= Etot) return;
    int s, d;
    if (e < E) { s = src[e]; d = dst[e]; }
    else       { s = d = e - E; }
    int pos = atomicAdd(&fill[d], 1);
    col[row_ptr[d] + pos] = s;
}

// ---------------- fp32 tiled GEMM:  C[m,n] = sum_k A[m,k]*B[n,k] (+bias[n]) ----------------
__global__ void gemm_nt(const float* __restrict__ A, const float* __restrict__ B,
                        const float* __restrict__ bias, float* __restrict__ C,
                        int M, int Nc, int K, int addBias) {
    __shared__ float As[16][64];
    __shared__ float Bs[16][64];
    int tid = threadIdx.x;           // 256 threads
    int row0 = blockIdx.y * 64;
    int col0 = blockIdx.x * 64;
    int tr = tid / 16;               // 0..15
    int tc = tid % 16;               // 0..15
    float acc[4][4] = {};
    int lm = tid / 4;                // 0..63
    int lk = (tid % 4) * 4;          // 0,4,8,12

    for (int k0 = 0; k0 < K; k0 += 16) {
        {
            int gr = row0 + lm;
            float4 v = make_float4(0.f, 0.f, 0.f, 0.f);
            if (gr < M) v = *(const float4*)(A + (size_t)gr * K + k0 + lk);
            As[lk + 0][lm] = v.x; As[lk + 1][lm] = v.y;
            As[lk + 2][lm] = v.z; As[lk + 3][lm] = v.w;
        }
        {
            int gc = col0 + lm;
            float4 v = make_float4(0.f, 0.f, 0.f, 0.f);
            if (gc < Nc) v = *(const float4*)(B + (size_t)gc * K + k0 + lk);
            Bs[lk + 0][lm] = v.x; Bs[lk + 1][lm] = v.y;
            Bs[lk + 2][lm] = v.z; Bs[lk + 3][lm] = v.w;
        }
        __syncthreads();
        #pragma unroll
        for (int k = 0; k < 16; ++k) {
            float4 a4 = *(const float4*)&As[k][tr * 4];
            float4 b4 = *(const float4*)&Bs[k][tc * 4];
            float a[4] = {a4.x, a4.y, a4.z, a4.w};
            float b[4] = {b4.x, b4.y, b4.z, b4.w};
            #pragma unroll
            for (int i = 0; i < 4; ++i)
                #pragma unroll
                for (int j = 0; j < 4; ++j)
                    acc[i][j] += a[i] * b[j];
        }
        __syncthreads();
    }
    #pragma unroll
    for (int i = 0; i < 4; ++i) {
        int gr = row0 + tr * 4 + i;
        if (gr >= M) continue;
        #pragma unroll
        for (int j = 0; j < 4; ++j) {
            int gc = col0 + tc * 4 + j;
            if (gc < Nc) {
                float v = acc[i][j];
                if (addBias) v += bias[gc];
                C[(size_t)gr * Nc + gc] = v;
            }
        }
    }
}

// ---------------- attention coefficients ----------------
__global__ void att_coef(const float* __restrict__ h, const float* __restrict__ att_src,
                         const float* __restrict__ att_dst, float* __restrict__ a_src,
                         float* __restrict__ a_dst, int N, int H) {
    int wave = threadIdx.x >> 6, lane = threadIdx.x & 63;
    int node = blockIdx.x * (blockDim.x >> 6) + wave;
    if (node >= N) return;
    for (int hh = 0; hh < H; ++hh) {
        float v = h[(size_t)node * H * 64 + hh * 64 + lane];
        float s1 = wave_sum(v * att_src[hh * 64 + lane]);
        float s2 = wave_sum(v * att_dst[hh * 64 + lane]);
        if (lane == 0) { a_src[node * H + hh] = s1; a_dst[node * H + hh] = s2; }
    }
}

// ---------------- GAT aggregation, H=4: block=node (256 thr), wave=whole edge row ----------------
// Phase 1-2: wave w computes softmax stats for head w (lanes stride edges).
// Phase 3: each wave loads a FULL 1KB source row (64 lanes x float4), waves stride edges by 4.
__global__ void gat_agg4(const float* __restrict__ h, const float* __restrict__ a_src,
                         const float* __restrict__ a_dst, const int* __restrict__ row_ptr,
                         const int* __restrict__ col, const float* __restrict__ bias,
                         float* __restrict__ out, int N) {
    int i = blockIdx.x;
    int w = threadIdx.x >> 6, lane = threadIdx.x & 63;
    int start = row_ptr[i], end = row_ptr[i + 1];

    __shared__ float ms[4], invs[4];
    __shared__ float accs[4][256];

    // phases 1-2: per-head softmax stats (wave w <-> head w)
    float ad = a_dst[i * 4 + w];
    float m = -1e30f;
    for (int j = start + lane; j < end; j += 64)
        m = fmaxf(m, leaky(a_src[col[j] * 4 + w] + ad));
    m = wave_max(m);
    float ssum = 0.0f;
    for (int j = start + lane; j < end; j += 64)
        ssum += __expf(leaky(a_src[col[j] * 4 + w] + ad) - m);
    ssum = wave_sum(ssum);
    if (lane == 0) { ms[w] = m; invs[w] = 1.0f / ssum; }
    __syncthreads();

    // phase 3: full-row gather, float4/lane
    int hh = lane >> 4;                    // this lane's head
    float mh = ms[hh], ih = invs[hh];
    float adh = a_dst[i * 4 + hh];
    float4 acc = make_float4(0.f, 0.f, 0.f, 0.f);
    for (int j = start + w; j < end; j += 4) {
        int s = col[j];
        float alpha = __expf(leaky(a_src[s * 4 + hh] + adh) - mh) * ih;
        float4 v = *(const float4*)(h + (size_t)s * 256 + lane * 4);
        acc.x += alpha * v.x; acc.y += alpha * v.y;
        acc.z += alpha * v.z; acc.w += alpha * v.w;
    }
    *(float4*)&accs[w][lane * 4] = acc;
    __syncthreads();

    int c = threadIdx.x;                   // 0..255 = output channel
    float sum = accs[0][c] + accs[1][c] + accs[2][c] + accs[3][c];
    out[(size_t)i * 256 + c] = leaky(sum + bias[c]);
}

// ---------------- GAT aggregation, H=1: 16-lane subgroup = edge, float4/lane ----------------
__global__ void gat_agg1h(const float* __restrict__ h, const float* __restrict__ a_src,
                          const float* __restrict__ a_dst, const int* __restrict__ row_ptr,
                          const int* __restrict__ col, const float* __restrict__ bias,
                          float* __restrict__ out, int N) {
    int i = blockIdx.x;
    int w = threadIdx.x >> 6, lane = threadIdx.x & 63;
    int start = row_ptr[i], end = row_ptr[i + 1];
    float ad = a_dst[i];

    // phases 1-2: computed redundantly per wave (no barrier needed)
    float m = -1e30f;
    for (int j = start + lane; j < end; j += 64)
        m = fmaxf(m, leaky(a_src[col[j]] + ad));
    m = wave_max(m);
    float ssum = 0.0f;
    for (int j = start + lane; j < end; j += 64)
        ssum += __expf(leaky(a_src[col[j]] + ad) - m);
    ssum = wave_sum(ssum);
    float inv = 1.0f / ssum;

    // phase 3: 4 subgroups x 4 waves = 16 edges in flight, float4/lane
    int sub = lane >> 4;
    int c4 = (lane & 15) * 4;
    float4 acc = make_float4(0.f, 0.f, 0.f, 0.f);
    for (int j = start + w * 4 + sub; j < end; j += 16) {
        int s = col[j];
        float alpha = __expf(leaky(a_src[s] + ad) - m) * inv;
        float4 v = *(const float4*)(h + (size_t)s * 64 + c4);
        acc.x += alpha * v.x; acc.y += alpha * v.y;
        acc.z += alpha * v.z; acc.w += alpha * v.w;
    }
    // reduce across the 4 subgroups (lanes with equal lane&15)
    #pragma unroll
    for (int o = 16; o <= 32; o <<= 1) {
        acc.x += __shfl_xor(acc.x, o, 64);
        acc.y += __shfl_xor(acc.y, o, 64);
        acc.z += __shfl_xor(acc.z, o, 64);
        acc.w += __shfl_xor(acc.w, o, 64);
    }
    __shared__ float accs[4][64];
    if (lane < 16) *(float4*)&accs[w][c4] = acc;
    __syncthreads();
    if (threadIdx.x < 64) {
        int c = threadIdx.x;
        float sum = accs[0][c] + accs[1][c] + accs[2][c] + accs[3][c];
        out[(size_t)i * 64 + c] = leaky(sum + bias[c]);
    }
}

// ---------------- leaky + LayerNorm + residual-add (in place on lin buffer) ----------------
__global__ void ln_res(const float* __restrict__ o2, float* __restrict__ lin,
                       const float* __restrict__ gamma, const float* __restrict__ beta, int N) {
    int wave = threadIdx.x >> 6, lane = threadIdx.x & 63;
    int i = blockIdx.x * (blockDim.x >> 6) + wave;
    if (i >= N) return;
    float x = o2[(size_t)i * 64 + lane];
    float mu = wave_sum(x) * (1.0f / 64.0f);
    float d = x - mu;
    float var = wave_sum(d * d) * (1.0f / 64.0f);
    float xn = d * rsqrtf(var + LN_EPS) * gamma[lane] + beta[lane];
    lin[(size_t)i * 64 + lane] += xn;
}

// ---------------- GRU gates + FC head ----------------
__global__ void gru_fc(const float* __restrict__ gi, const float* __restrict__ b_hh,
                       const float* __restrict__ fc_w, const float* __restrict__ fc_b,
                       float* __restrict__ outp, int N) {
    int wave = threadIdx.x >> 6, lane = threadIdx.x & 63;
    int i = blockIdx.x * (blockDim.x >> 6) + wave;
    if (i >= N) return;
    const float* g = gi + (size_t)i * 192;
    float i_r = g[lane], i_z = g[64 + lane], i_n = g[128 + lane];
    float r = 1.0f / (1.0f + __expf(-(i_r + b_hh[lane])));
    float z = 1.0f / (1.0f + __expf(-(i_z + b_hh[64 + lane])));
    float ng = tanhf(i_n + r * b_hh[128 + lane]);
    float hy = (1.0f - z) * ng;
    #pragma unroll
    for (int k = 0; k < 3; ++k) {
        float s = wave_sum(hy * fc_w[k * 64 + lane]);
        if (lane == 0) outp[(size_t)i * 3 + k] = s + fc_b[k];
    }
}

extern "C" void kernel_launch(void* const* d_in, const int* in_sizes, int n_in,
                              void* d_out, int out_size, void* d_ws, size_t ws_size,
                              hipStream_t stream) {
    const float* x        = (const float*)d_in[0];
    const int*   ei       = (const int*)d_in[1];
    const float* W1       = (const float*)d_in[2];
    const float* att_src1 = (const float*)d_in[3];
    const float* att_dst1 = (const float*)d_in[4];
    const float* b1       = (const float*)d_in[5];
    const float* W2       = (const float*)d_in[6];
    const float* att_src2 = (const float*)d_in[7];
    const float* att_dst2 = (const float*)d_in[8];
    const float* b2       = (const float*)d_in[9];
    const float* lin_w    = (const float*)d_in[10];
    const float* lin_b    = (const float*)d_in[11];
    const float* gamma    = (const float*)d_in[12];
    const float* beta     = (const float*)d_in[13];
    const float* w_ih     = (const float*)d_in[14];
    // d_in[15] = w_hh (unused: h0 == 0)
    const float* b_ih     = (const float*)d_in[16];
    const float* b_hh     = (const float*)d_in[17];
    const float* fc_w     = (const float*)d_in[18];
    const float* fc_b     = (const float*)d_in[19];
    float* out = (float*)d_out;

    const int N = N_NODES, E = N_EDGES;
    const int Etot = E + N;
    char* ws = (char*)d_ws;

    size_t off = 0;
    auto alloc = [&](size_t bytes) {
        size_t o = off;
        off = (off + bytes + 255) & ~(size_t)255;
        return o;
    };
    int*   row_ptr = (int*)(ws + alloc((size_t)(N + 1) * 4));
    int*   col     = (int*)(ws + alloc((size_t)Etot * 4));
    int*   deg     = (int*)(ws + alloc((size_t)N * 4));
    int*   fill    = (int*)(ws + alloc((size_t)N * 4));
    float* a_src1b = (float*)(ws + alloc((size_t)N * HEADS * 4));
    float* a_dst1b = (float*)(ws + alloc((size_t)N * HEADS * 4));
    float* a_src2b = (float*)(ws + alloc((size_t)N * 4));
    float* a_dst2b = (float*)(ws + alloc((size_t)N * 4));
    float* h1      = (float*)(ws + alloc((size_t)N * 256 * 4));   // region A (51.2MB)
    float* o1      = (float*)(ws + alloc((size_t)N * 256 * 4));   // region B (51.2MB)
    // region-A aliases (valid only AFTER h1's [N,256] content is dead, i.e. after gat_agg4):
    float* h2  = h1;                                              // [N,64]  (12.8MB)
    float* o2  = (float*)((char*)h1 + (size_t)16 * 1024 * 1024);  // [N,64]  at +16MB
    float* lin = (float*)((char*)h1 + (size_t)32 * 1024 * 1024);  // [N,64]  at +32MB
    // region-B alias (valid after gemm2 consumed o1):
    float* gi  = o1;                                              // [N,192] (38.4MB)

    hipMemsetAsync(deg, 0, (size_t)N * 4, stream);
    hipMemsetAsync(fill, 0, (size_t)N * 4, stream);

    // ---- CSR build (shared by both GAT layers) ----
    count_kernel<<<(Etot + 255) / 256, 256, 0, stream>>>(ei + E, deg, E, Etot);
    scan_kernel<<<1, 1024, 0, stream>>>(deg, row_ptr, N);
    scatter_kernel<<<(Etot + 255) / 256, 256, 0, stream>>>(ei, ei + E, row_ptr, fill, col, E, Etot);

    // ---- GAT layer 1 ----
    dim3 g1(4, (N + 63) / 64);
    gemm_nt<<<g1, 256, 0, stream>>>(x, W1, nullptr, h1, N, 256, 256, 0);
    att_coef<<<(N + 3) / 4, 256, 0, stream>>>(h1, att_src1, att_dst1, a_src1b, a_dst1b, N, HEADS);
    gat_agg4<<<N, 256, 0, stream>>>(h1, a_src1b, a_dst1b, row_ptr, col, b1, o1, N);

    // ---- lin residual projection (after gat_agg4: lin aliases region A) ----
    dim3 gLin(1, (N + 63) / 64);
    gemm_nt<<<gLin, 256, 0, stream>>>(x, lin_w, lin_b, lin, N, 64, 256, 1);

    // ---- GAT layer 2 ----
    dim3 g2(1, (N + 63) / 64);
    gemm_nt<<<g2, 256, 0, stream>>>(o1, W2, nullptr, h2, N, 64, 256, 0);
    att_coef<<<(N + 3) / 4, 256, 0, stream>>>(h2, att_src2, att_dst2, a_src2b, a_dst2b, N, 1);
    gat_agg1h<<<N, 256, 0, stream>>>(h2, a_src2b, a_dst2b, row_ptr, col, b2, o2, N);

    // ---- LayerNorm + residual ----
    ln_res<<<(N + 3) / 4, 256, 0, stream>>>(o2, lin, gamma, beta, N);

    // ---- GRU input GEMM: gi = hres @ w_ih^T + b_ih ----
    dim3 g3(3, (N + 63) / 64);
    gemm_nt<<<g3, 256, 0, stream>>>(lin, w_ih, b_ih, gi, N, 192, 64, 1);

    // ---- GRU gates + FC head ----
    gru_fc<<<(N + 3) / 4, 256, 0, stream>>>(gi, b_hh, fc_w, fc_b, out, N);
}

// Round 4
// 697.568 us; speedup vs baseline: 1.2064x; 1.1330x over previous
//
#include <hip/hip_runtime.h>
#include <hip/hip_bf16.h>

#define N_NODES 50000
#define N_EDGES 800000
#define F_IN 256
#define HID 64
#define HEADS 4
#define NEG 0.2f
#define LN_EPS 1e-5f

typedef _Float16 half8 __attribute__((ext_vector_type(8)));
typedef _Float16 half4v __attribute__((ext_vector_type(4)));
typedef float floatx4 __attribute__((ext_vector_type(4)));

__device__ __forceinline__ float wave_sum(float v) {
    #pragma unroll
    for (int o = 32; o > 0; o >>= 1) v += __shfl_xor(v, o, 64);
    return v;
}
__device__ __forceinline__ float leaky(float x) { return x > 0.0f ? x : NEG * x; }

// ---------------- CSR build ----------------
__global__ void count_kernel(const int* __restrict__ dst, int* __restrict__ deg,
                             int E, int Etot) {
    int e = blockIdx.x * blockDim.x + threadIdx.x;
    if (e >= Etot) return;
    int d = (e < E) ? dst[e] : (e - E);   // tail = self loops
    atomicAdd(&deg[d], 1);
}

__global__ void scan_kernel(const int* __restrict__ deg, int* __restrict__ row_ptr, int N) {
    __shared__ int part[1024];
    int t = threadIdx.x;
    int chunk = (N + 1023) / 1024;
    int base = t * chunk;
    int local = 0;
    for (int j = 0; j < chunk; ++j) {
        int idx = base + j;
        if (idx < N) local += deg[idx];
    }
    part[t] = local;
    __syncthreads();
    for (int off = 1; off < 1024; off <<= 1) {
        int v = 0;
        if (t >= off) v = part[t - off];
        __syncthreads();
        part[t] += v;
        __syncthreads();
    }
    int run = (t == 0) ? 0 : part[t - 1];
    for (int j = 0; j < chunk; ++j) {
        int idx = base + j;
        if (idx < N) { run += deg[idx]; row_ptr[idx + 1] = run; }
    }
    if (t == 0) row_ptr[0] = 0;
}

__global__ void scatter_kernel(const int* __restrict__ src, const int* __restrict__ dst,
                               const int* __restrict__ row_ptr, int* __restrict__ fill,
                               int* __restrict__ col, int E, int Etot) {
    int e = blockIdx.x * blockDim.x + threadIdx.x;
    if (e >= Etot) return;
    int s, d;
    if (e < E) { s = src[e]; d = dst[e]; }
    else       { s = d = e - E; }
    int pos = atomicAdd(&fill[d], 1);
    col[row_ptr[d] + pos] = s;
}

// ---------------- fp32 -> fp16 conversion (n % 4 == 0) ----------------
__global__ void cvt_f16(const float* __restrict__ in, _Float16* __restrict__ outp, int n) {
    int idx = (blockIdx.x * blockDim.x + threadIdx.x) * 4;
    if (idx >= n) return;
    float4 v = *(const float4*)(in + idx);
    half4v h;
    h[0] = (_Float16)v.x; h[1] = (_Float16)v.y;
    h[2] = (_Float16)v.z; h[3] = (_Float16)v.w;
    *(half4v*)(outp + idx) = h;
}

// ---------------- fp16 MFMA GEMM: C[M, NT*16] = A[M,K] @ B[NT*16, K]^T (+bias) ----------------
// A,B fp16 row-major. Block = 256 thr = 4 waves; wave w does rows [bx*64+w*16, +16) x all cols.
// A read once per block; B (<=128KB) stays L2-hot. No LDS, no barriers.
// Fragment layouts (verified m89/m120): A[m=lane&15][k=quad*8+j], B_op[k=quad*8+j][n=lane&15]
// (= row-major B[n][k] contiguous read), C: col=lane&15, row=quad*4+reg.
template<int NT>
__global__ void gemm_mfma(const _Float16* __restrict__ A, const _Float16* __restrict__ B,
                          const float* __restrict__ bias, void* __restrict__ Cout,
                          int M, int K, int out_f16, int add_bias) {
    int w = threadIdx.x >> 6, lane = threadIdx.x & 63;
    int m_base = blockIdx.x * 64 + w * 16;
    if (m_base >= M) return;                 // M % 16 == 0 -> uniform per wave
    int r = lane & 15, q = lane >> 4;
    const _Float16* ap = A + (size_t)(m_base + r) * K + q * 8;
    const _Float16* bp = B + (size_t)r * K + q * 8;
    floatx4 acc[NT];
    #pragma unroll
    for (int t = 0; t < NT; ++t) acc[t] = (floatx4){0.f, 0.f, 0.f, 0.f};
    for (int k0 = 0; k0 < K; k0 += 32) {
        half8 a = *(const half8*)(ap + k0);
        #pragma unroll
        for (int t = 0; t < NT; ++t) {
            half8 b = *(const half8*)(bp + (size_t)t * 16 * K + k0);
            acc[t] = __builtin_amdgcn_mfma_f32_16x16x32_f16(a, b, acc[t], 0, 0, 0);
        }
    }
    const int Nc = NT * 16;
    #pragma unroll
    for (int t = 0; t < NT; ++t) {
        int cc = t * 16 + r;
        float bv = add_bias ? bias[cc] : 0.0f;
        #pragma unroll
        for (int rr = 0; rr < 4; ++rr) {
            int gm = m_base + q * 4 + rr;
            float v = acc[t][rr] + bv;
            if (out_f16) ((_Float16*)Cout)[(size_t)gm * Nc + cc] = (_Float16)v;
            else         ((float*)Cout)[(size_t)gm * Nc + cc] = v;
        }
    }
}

// ---------------- attention coefficients (h fp16) ----------------
__global__ void att_coef(const _Float16* __restrict__ h, const float* __restrict__ att_src,
                         const float* __restrict__ att_dst, float* __restrict__ a_src,
                         float* __restrict__ a_dst, int N, int H) {
    int wave = threadIdx.x >> 6, lane = threadIdx.x & 63;
    int node = blockIdx.x * (blockDim.x >> 6) + wave;
    if (node >= N) return;
    for (int hh = 0; hh < H; ++hh) {
        float v = (float)h[(size_t)node * H * 64 + hh * 64 + lane];
        float s1 = wave_sum(v * att_src[hh * 64 + lane]);
        float s2 = wave_sum(v * att_dst[hh * 64 + lane]);
        if (lane == 0) { a_src[node * H + hh] = s1; a_dst[node * H + hh] = s2; }
    }
}

// ---------------- GAT aggregation, H=4, fp16 rows, no max-pass ----------------
__global__ void gat_agg4(const _Float16* __restrict__ h, const float* __restrict__ a_src,
                         const float* __restrict__ a_dst, const int* __restrict__ row_ptr,
                         const int* __restrict__ col, const float* __restrict__ bias,
                         _Float16* __restrict__ outp, int N) {
    int i = blockIdx.x;
    int w = threadIdx.x >> 6, lane = threadIdx.x & 63;
    int start = row_ptr[i], end = row_ptr[i + 1];

    __shared__ float invs[4];
    __shared__ float accs[4][256];

    // denom (softmax is shift-invariant; logits |e| <~ 2, exp safe)
    float ad = a_dst[i * 4 + w];
    float ssum = 0.0f;
    for (int j = start + lane; j < end; j += 64)
        ssum += __expf(leaky(a_src[col[j] * 4 + w] + ad));
    ssum = wave_sum(ssum);
    if (lane == 0) invs[w] = 1.0f / ssum;
    __syncthreads();

    // full-row gather: 64 lanes x half4 (8B) = 512B row; waves stride edges by 4
    int hh = lane >> 4;
    float ih = invs[hh];
    float adh = a_dst[i * 4 + hh];
    float4 acc = make_float4(0.f, 0.f, 0.f, 0.f);
    for (int j = start + w; j < end; j += 4) {
        int s = col[j];
        float alpha = __expf(leaky(a_src[s * 4 + hh] + adh)) * ih;
        half4v v = *(const half4v*)(h + (size_t)s * 256 + lane * 4);
        acc.x += alpha * (float)v[0]; acc.y += alpha * (float)v[1];
        acc.z += alpha * (float)v[2]; acc.w += alpha * (float)v[3];
    }
    *(float4*)&accs[w][lane * 4] = acc;
    __syncthreads();

    int c = threadIdx.x;
    float sum = accs[0][c] + accs[1][c] + accs[2][c] + accs[3][c];
    outp[(size_t)i * 256 + c] = (_Float16)leaky(sum + bias[c]);
}

// ---------------- GAT aggregation, H=1, fp16 rows, no max-pass ----------------
__global__ void gat_agg1h(const _Float16* __restrict__ h, const float* __restrict__ a_src,
                          const float* __restrict__ a_dst, const int* __restrict__ row_ptr,
                          const int* __restrict__ col, const float* __restrict__ bias,
                          float* __restrict__ outp, int N) {
    int i = blockIdx.x;
    int w = threadIdx.x >> 6, lane = threadIdx.x & 63;
    int start = row_ptr[i], end = row_ptr[i + 1];
    float ad = a_dst[i];

    float ssum = 0.0f;
    for (int j = start + lane; j < end; j += 64)
        ssum += __expf(leaky(a_src[col[j]] + ad));
    ssum = wave_sum(ssum);
    float inv = 1.0f / ssum;

    // 4 subgroups x 4 waves = 16 edges in flight; 16 lanes x half4 (8B) = 128B row
    int sub = lane >> 4;
    int c4 = (lane & 15) * 4;
    float4 acc = make_float4(0.f, 0.f, 0.f, 0.f);
    for (int j = start + w * 4 + sub; j < end; j += 16) {
        int s = col[j];
        float alpha = __expf(leaky(a_src[s] + ad)) * inv;
        half4v v = *(const half4v*)(h + (size_t)s * 64 + c4);
        acc.x += alpha * (float)v[0]; acc.y += alpha * (float)v[1];
        acc.z += alpha * (float)v[2]; acc.w += alpha * (float)v[3];
    }
    #pragma unroll
    for (int o = 16; o <= 32; o <<= 1) {
        acc.x += __shfl_xor(acc.x, o, 64);
        acc.y += __shfl_xor(acc.y, o, 64);
        acc.z += __shfl_xor(acc.z, o, 64);
        acc.w += __shfl_xor(acc.w, o, 64);
    }
    __shared__ float accs[4][64];
    if (lane < 16) *(float4*)&accs[w][c4] = acc;
    __syncthreads();
    if (threadIdx.x < 64) {
        int c = threadIdx.x;
        float sum = accs[0][c] + accs[1][c] + accs[2][c] + accs[3][c];
        outp[(size_t)i * 64 + c] = leaky(sum + bias[c]);
    }
}

// ---------------- leaky'd o2 -> LayerNorm -> + residual(lin) -> hres fp16 ----------------
__global__ void ln_res(const float* __restrict__ o2, const float* __restrict__ lin,
                       _Float16* __restrict__ hresh,
                       const float* __restrict__ gamma, const float* __restrict__ beta, int N) {
    int wave = threadIdx.x >> 6, lane = threadIdx.x & 63;
    int i = blockIdx.x * (blockDim.x >> 6) + wave;
    if (i >= N) return;
    float x = o2[(size_t)i * 64 + lane];
    float mu = wave_sum(x) * (1.0f / 64.0f);
    float d = x - mu;
    float var = wave_sum(d * d) * (1.0f / 64.0f);
    float xn = d * rsqrtf(var + LN_EPS) * gamma[lane] + beta[lane];
    float v = lin[(size_t)i * 64 + lane] + xn;
    hresh[(size_t)i * 64 + lane] = (_Float16)v;
}

// ---------------- GRU gates + FC head ----------------
__global__ void gru_fc(const float* __restrict__ gi, const float* __restrict__ b_hh,
                       const float* __restrict__ fc_w, const float* __restrict__ fc_b,
                       float* __restrict__ outp, int N) {
    int wave = threadIdx.x >> 6, lane = threadIdx.x & 63;
    int i = blockIdx.x * (blockDim.x >> 6) + wave;
    if (i >= N) return;
    const float* g = gi + (size_t)i * 192;
    float i_r = g[lane], i_z = g[64 + lane], i_n = g[128 + lane];
    float r = 1.0f / (1.0f + __expf(-(i_r + b_hh[lane])));
    float z = 1.0f / (1.0f + __expf(-(i_z + b_hh[64 + lane])));
    float ng = tanhf(i_n + r * b_hh[128 + lane]);
    float hy = (1.0f - z) * ng;
    #pragma unroll
    for (int k = 0; k < 3; ++k) {
        float s = wave_sum(hy * fc_w[k * 64 + lane]);
        if (lane == 0) outp[(size_t)i * 3 + k] = s + fc_b[k];
    }
}

extern "C" void kernel_launch(void* const* d_in, const int* in_sizes, int n_in,
                              void* d_out, int out_size, void* d_ws, size_t ws_size,
                              hipStream_t stream) {
    const float* x        = (const float*)d_in[0];
    const int*   ei       = (const int*)d_in[1];
    const float* W1       = (const float*)d_in[2];
    const float* att_src1 = (const float*)d_in[3];
    const float* att_dst1 = (const float*)d_in[4];
    const float* b1       = (const float*)d_in[5];
    const float* W2       = (const float*)d_in[6];
    const float* att_src2 = (const float*)d_in[7];
    const float* att_dst2 = (const float*)d_in[8];
    const float* b2       = (const float*)d_in[9];
    const float* lin_w    = (const float*)d_in[10];
    const float* lin_b    = (const float*)d_in[11];
    const float* gamma    = (const float*)d_in[12];
    const float* beta     = (const float*)d_in[13];
    const float* w_ih     = (const float*)d_in[14];
    // d_in[15] = w_hh (unused: h0 == 0)
    const float* b_ih     = (const float*)d_in[16];
    const float* b_hh     = (const float*)d_in[17];
    const float* fc_w     = (const float*)d_in[18];
    const float* fc_b     = (const float*)d_in[19];
    float* out = (float*)d_out;

    const int N = N_NODES, E = N_EDGES;
    const int Etot = E + N;
    char* ws = (char*)d_ws;

    size_t off = 0;
    auto alloc = [&](size_t bytes) {
        size_t o = off;
        off = (off + bytes + 255) & ~(size_t)255;
        return o;
    };
    int*      row_ptr = (int*)(ws + alloc((size_t)(N + 1) * 4));
    int*      col     = (int*)(ws + alloc((size_t)Etot * 4));
    int*      deg     = (int*)(ws + alloc((size_t)N * 4));
    int*      fill    = (int*)(ws + alloc((size_t)N * 4));
    float*    a_src1b = (float*)(ws + alloc((size_t)N * HEADS * 4));
    float*    a_dst1b = (float*)(ws + alloc((size_t)N * HEADS * 4));
    float*    a_src2b = (float*)(ws + alloc((size_t)N * 4));
    float*    a_dst2b = (float*)(ws + alloc((size_t)N * 4));
    _Float16* W1h     = (_Float16*)(ws + alloc((size_t)256 * 256 * 2));
    _Float16* W2h     = (_Float16*)(ws + alloc((size_t)64 * 256 * 2));
    _Float16* lin_wh  = (_Float16*)(ws + alloc((size_t)64 * 256 * 2));
    _Float16* w_ihh   = (_Float16*)(ws + alloc((size_t)192 * 64 * 2));
    // big region (64MB): xh@0 (25.6M), h1h@25.6M (25.6M), lin@51.2M (12.8M).
    // gi (fp32, 38.4M) aliases [0, 38.4M) AFTER xh & h1h are dead; lin untouched.
    char* big = ws + alloc((size_t)64000000);
    _Float16* xh   = (_Float16*)big;
    _Float16* h1h  = (_Float16*)(big + 25600000);
    float*    lin  = (float*)(big + 51200000);
    float*    gi   = (float*)big;
    // region r3 (25.6M): o1h (fp16 [N,256]); after gemm2 consumes it, reused as o2 (fp32 [N,64])
    char* r3 = ws + alloc((size_t)25600000);
    _Float16* o1h = (_Float16*)r3;
    float*    o2  = (float*)r3;
    // region r4 (6.4M): h2h (fp16 [N,64]); after gat_agg1h, reused as hresh (fp16 [N,64])
    char* r4 = ws + alloc((size_t)6400000);
    _Float16* h2h   = (_Float16*)r4;
    _Float16* hresh = (_Float16*)r4;

    hipMemsetAsync(deg, 0, (size_t)N * 4, stream);
    hipMemsetAsync(fill, 0, (size_t)N * 4, stream);

    // ---- CSR build ----
    count_kernel<<<(Etot + 255) / 256, 256, 0, stream>>>(ei + E, deg, E, Etot);
    scan_kernel<<<1, 1024, 0, stream>>>(deg, row_ptr, N);
    scatter_kernel<<<(Etot + 255) / 256, 256, 0, stream>>>(ei, ei + E, row_ptr, fill, col, E, Etot);

    // ---- fp16 conversions ----
    cvt_f16<<<(N * F_IN / 4 + 255) / 256, 256, 0, stream>>>(x, xh, N * F_IN);
    cvt_f16<<<(256 * 256 / 4 + 255) / 256, 256, 0, stream>>>(W1, W1h, 256 * 256);
    cvt_f16<<<(64 * 256 / 4 + 255) / 256, 256, 0, stream>>>(W2, W2h, 64 * 256);
    cvt_f16<<<(64 * 256 / 4 + 255) / 256, 256, 0, stream>>>(lin_w, lin_wh, 64 * 256);
    cvt_f16<<<(192 * 64 / 4 + 255) / 256, 256, 0, stream>>>(w_ih, w_ihh, 192 * 64);

    const int gmBlocks = (N + 63) / 64;   // 782

    // ---- GAT layer 1 ----
    gemm_mfma<16><<<gmBlocks, 256, 0, stream>>>(xh, W1h, nullptr, h1h, N, 256, 1, 0);
    att_coef<<<(N + 3) / 4, 256, 0, stream>>>(h1h, att_src1, att_dst1, a_src1b, a_dst1b, N, HEADS);
    gat_agg4<<<N, 256, 0, stream>>>(h1h, a_src1b, a_dst1b, row_ptr, col, b1, o1h, N);

    // ---- residual projection: lin = x @ lin_w^T + lin_b (fp32 out) ----
    gemm_mfma<4><<<gmBlocks, 256, 0, stream>>>(xh, lin_wh, lin_b, lin, N, 256, 0, 1);

    // ---- GAT layer 2 ----
    gemm_mfma<4><<<gmBlocks, 256, 0, stream>>>(o1h, W2h, nullptr, h2h, N, 256, 1, 0);
    att_coef<<<(N + 3) / 4, 256, 0, stream>>>(h2h, att_src2, att_dst2, a_src2b, a_dst2b, N, 1);
    gat_agg1h<<<N, 256, 0, stream>>>(h2h, a_src2b, a_dst2b, row_ptr, col, b2, o2, N);

    // ---- LayerNorm + residual -> hres fp16 ----
    ln_res<<<(N + 3) / 4, 256, 0, stream>>>(o2, lin, hresh, gamma, beta, N);

    // ---- GRU input GEMM: gi = hres @ w_ih^T + b_ih (fp32 out) ----
    gemm_mfma<12><<<gmBlocks, 256, 0, stream>>>(hresh, w_ihh, b_ih, gi, N, 64, 0, 1);

    // ---- GRU gates + FC head ----
    gru_fc<<<(N + 3) / 4, 256, 0, stream>>>(gi, b_hh, fc_w, fc_b, out, N);
}

// Round 5
// 631.492 us; speedup vs baseline: 1.3327x; 1.1046x over previous
//
#include <hip/hip_runtime.h>
#include <hip/hip_bf16.h>

#define N_NODES 50000
#define N_EDGES 800000
#define F_IN 256
#define HID 64
#define HEADS 4
#define NEG 0.2f
#define LN_EPS 1e-5f

typedef _Float16 half8 __attribute__((ext_vector_type(8)));
typedef _Float16 half4v __attribute__((ext_vector_type(4)));
typedef float floatx4 __attribute__((ext_vector_type(4)));

__device__ __forceinline__ float wave_sum(float v) {
    #pragma unroll
    for (int o = 32; o > 0; o >>= 1) v += __shfl_xor(v, o, 64);
    return v;
}
__device__ __forceinline__ float leaky(float x) { return x > 0.0f ? x : NEG * x; }

// ---------------- CSR build ----------------
__global__ void count_kernel(const int* __restrict__ dst, int* __restrict__ deg,
                             int E, int Etot) {
    int e = blockIdx.x * blockDim.x + threadIdx.x;
    if (e >= Etot) return;
    int d = (e < E) ? dst[e] : (e - E);   // tail = self loops
    atomicAdd(&deg[d], 1);
}

__global__ void scan_kernel(const int* __restrict__ deg, int* __restrict__ row_ptr, int N) {
    __shared__ int part[1024];
    int t = threadIdx.x;
    int chunk = (N + 1023) / 1024;
    int base = t * chunk;
    int local = 0;
    for (int j = 0; j < chunk; ++j) {
        int idx = base + j;
        if (idx < N) local += deg[idx];
    }
    part[t] = local;
    __syncthreads();
    for (int off = 1; off < 1024; off <<= 1) {
        int v = 0;
        if (t >= off) v = part[t - off];
        __syncthreads();
        part[t] += v;
        __syncthreads();
    }
    int run = (t == 0) ? 0 : part[t - 1];
    for (int j = 0; j < chunk; ++j) {
        int idx = base + j;
        if (idx < N) { run += deg[idx]; row_ptr[idx + 1] = run; }
    }
    if (t == 0) row_ptr[0] = 0;
}

__global__ void scatter_kernel(const int* __restrict__ src, const int* __restrict__ dst,
                               const int* __restrict__ row_ptr, int* __restrict__ fill,
                               int* __restrict__ col, int E, int Etot) {
    int e = blockIdx.x * blockDim.x + threadIdx.x;
    if (e >= Etot) return;
    int s, d;
    if (e < E) { s = src[e]; d = dst[e]; }
    else       { s = d = e - E; }
    int pos = atomicAdd(&fill[d], 1);
    col[row_ptr[d] + pos] = s;
}

// ---------------- merged fp32 -> fp16 conversion over 5 ranges ----------------
struct CvtJob { const float* src; _Float16* dst; int len; };
__global__ void cvt_f16_multi(CvtJob j0, CvtJob j1, CvtJob j2, CvtJob j3, CvtJob j4) {
    int idx = (blockIdx.x * blockDim.x + threadIdx.x) * 4;
    const float* s; _Float16* d; int rel = idx;
    if      (rel < j0.len) { s = j0.src; d = j0.dst; }
    else if ((rel -= j0.len) < j1.len) { s = j1.src; d = j1.dst; }
    else if ((rel -= j1.len) < j2.len) { s = j2.src; d = j2.dst; }
    else if ((rel -= j2.len) < j3.len) { s = j3.src; d = j3.dst; }
    else if ((rel -= j3.len) < j4.len) { s = j4.src; d = j4.dst; }
    else return;
    float4 v = *(const float4*)(s + rel);
    half4v h;
    h[0] = (_Float16)v.x; h[1] = (_Float16)v.y;
    h[2] = (_Float16)v.z; h[3] = (_Float16)v.w;
    *(half4v*)(d + rel) = h;
}

// ---------------- fp16 MFMA GEMM + optional fused attention-coefficient epilogue ----------
// C[M, NT*16] = A[M,K] @ B[NT*16,K]^T (+bias). Block=256thr=4 waves; wave w: rows
// [bx*64+w*16,+16) x all cols. Fragment layouts verified (m89/m120): A[m=lane&15][k=q*8+j],
// C: col=lane&15, row=q*4+reg. If H>0: also emit a_src/a_dst [M,H] from the fp32
// accumulators (head h = cols [h*64,(h+1)*64) = tiles 4h..4h+3).
template<int NT, int H>
__global__ void gemm_mfma(const _Float16* __restrict__ A, const _Float16* __restrict__ B,
                          const float* __restrict__ bias, void* __restrict__ Cout,
                          const float* __restrict__ att_s, const float* __restrict__ att_d,
                          float* __restrict__ a_srcO, float* __restrict__ a_dstO,
                          int M, int K, int out_f16, int add_bias) {
    int w = threadIdx.x >> 6, lane = threadIdx.x & 63;
    int m_base = blockIdx.x * 64 + w * 16;
    if (m_base >= M) return;                 // M % 16 == 0 -> uniform per wave
    int r = lane & 15, q = lane >> 4;
    const _Float16* ap = A + (size_t)(m_base + r) * K + q * 8;
    const _Float16* bp = B + (size_t)r * K + q * 8;
    floatx4 acc[NT];
    #pragma unroll
    for (int t = 0; t < NT; ++t) acc[t] = (floatx4){0.f, 0.f, 0.f, 0.f};
    for (int k0 = 0; k0 < K; k0 += 32) {
        half8 a = *(const half8*)(ap + k0);
        #pragma unroll
        for (int t = 0; t < NT; ++t) {
            half8 b = *(const half8*)(bp + (size_t)t * 16 * K + k0);
            acc[t] = __builtin_amdgcn_mfma_f32_16x16x32_f16(a, b, acc[t], 0, 0, 0);
        }
    }
    const int Nc = NT * 16;
    #pragma unroll
    for (int t = 0; t < NT; ++t) {
        int cc = t * 16 + r;
        float bv = add_bias ? bias[cc] : 0.0f;
        #pragma unroll
        for (int rr = 0; rr < 4; ++rr) {
            int gm = m_base + q * 4 + rr;
            float v = acc[t][rr] + bv;
            if (out_f16) ((_Float16*)Cout)[(size_t)gm * Nc + cc] = (_Float16)v;
            else         ((float*)Cout)[(size_t)gm * Nc + cc] = v;
        }
    }
    if constexpr (H > 0) {
        // per-lane partial dots over this lane's columns (t*16+r)
        float ps[H][4], pd[H][4];
        #pragma unroll
        for (int h = 0; h < H; ++h) {
            #pragma unroll
            for (int rr = 0; rr < 4; ++rr) { ps[h][rr] = 0.f; pd[h][rr] = 0.f; }
            #pragma unroll
            for (int tt = 0; tt < 4; ++tt) {
                int t = h * 4 + tt;
                float as = att_s[t * 16 + r];
                float ad = att_d[t * 16 + r];
                #pragma unroll
                for (int rr = 0; rr < 4; ++rr) {
                    ps[h][rr] += acc[t][rr] * as;
                    pd[h][rr] += acc[t][rr] * ad;
                }
            }
        }
        // reduce over the 16 lanes of each quad (xor within bits 0..3)
        #pragma unroll
        for (int m = 1; m < 16; m <<= 1) {
            #pragma unroll
            for (int h = 0; h < H; ++h)
                #pragma unroll
                for (int rr = 0; rr < 4; ++rr) {
                    ps[h][rr] += __shfl_xor(ps[h][rr], m, 64);
                    pd[h][rr] += __shfl_xor(pd[h][rr], m, 64);
                }
        }
        if (r == 0) {
            #pragma unroll
            for (int rr = 0; rr < 4; ++rr) {
                int gm = m_base + q * 4 + rr;
                #pragma unroll
                for (int h = 0; h < H; ++h) {
                    a_srcO[gm * H + h] = ps[h][rr];
                    a_dstO[gm * H + h] = pd[h][rr];
                }
            }
        }
    }
}

// ---------------- GAT aggregation, H=4, fp16 rows, no max-pass, 4-deep edge batching -------
__global__ void gat_agg4(const _Float16* __restrict__ h, const float* __restrict__ a_src,
                         const float* __restrict__ a_dst, const int* __restrict__ row_ptr,
                         const int* __restrict__ col, const float* __restrict__ bias,
                         _Float16* __restrict__ outp, int N) {
    int i = blockIdx.x;
    int w = threadIdx.x >> 6, lane = threadIdx.x & 63;
    int start = row_ptr[i], end = row_ptr[i + 1];

    __shared__ float invs[4];
    __shared__ float accs[4][256];

    // denom (softmax shift-invariant; logits small, exp safe)
    float ad = a_dst[i * 4 + w];
    float ssum = 0.0f;
    for (int j = start + lane; j < end; j += 64)
        ssum += __expf(leaky(a_src[col[j] * 4 + w] + ad));
    ssum = wave_sum(ssum);
    if (lane == 0) invs[w] = 1.0f / ssum;
    __syncthreads();

    // full-row gather: 64 lanes x half4 (8B) = 512B/row; waves stride edges by 4;
    // 4 edges batched per iteration for memory-level parallelism.
    int hh = lane >> 4;
    float ih = invs[hh];
    float adh = a_dst[i * 4 + hh];
    float4 acc = make_float4(0.f, 0.f, 0.f, 0.f);
    int j = start + w;
    for (; j + 12 < end; j += 16) {
        int s0 = col[j], s1 = col[j + 4], s2 = col[j + 8], s3 = col[j + 12];
        float e0 = a_src[s0 * 4 + hh], e1 = a_src[s1 * 4 + hh];
        float e2 = a_src[s2 * 4 + hh], e3 = a_src[s3 * 4 + hh];
        half4v v0 = *(const half4v*)(h + (size_t)s0 * 256 + lane * 4);
        half4v v1 = *(const half4v*)(h + (size_t)s1 * 256 + lane * 4);
        half4v v2 = *(const half4v*)(h + (size_t)s2 * 256 + lane * 4);
        half4v v3 = *(const half4v*)(h + (size_t)s3 * 256 + lane * 4);
        float a0 = __expf(leaky(e0 + adh)) * ih;
        float a1 = __expf(leaky(e1 + adh)) * ih;
        float a2 = __expf(leaky(e2 + adh)) * ih;
        float a3 = __expf(leaky(e3 + adh)) * ih;
        acc.x += a0 * (float)v0[0] + a1 * (float)v1[0] + a2 * (float)v2[0] + a3 * (float)v3[0];
        acc.y += a0 * (float)v0[1] + a1 * (float)v1[1] + a2 * (float)v2[1] + a3 * (float)v3[1];
        acc.z += a0 * (float)v0[2] + a1 * (float)v1[2] + a2 * (float)v2[2] + a3 * (float)v3[2];
        acc.w += a0 * (float)v0[3] + a1 * (float)v1[3] + a2 * (float)v2[3] + a3 * (float)v3[3];
    }
    for (; j < end; j += 4) {
        int s = col[j];
        float alpha = __expf(leaky(a_src[s * 4 + hh] + adh)) * ih;
        half4v v = *(const half4v*)(h + (size_t)s * 256 + lane * 4);
        acc.x += alpha * (float)v[0]; acc.y += alpha * (float)v[1];
        acc.z += alpha * (float)v[2]; acc.w += alpha * (float)v[3];
    }
    *(float4*)&accs[w][lane * 4] = acc;
    __syncthreads();

    int c = threadIdx.x;
    float sum = accs[0][c] + accs[1][c] + accs[2][c] + accs[3][c];
    outp[(size_t)i * 256 + c] = (_Float16)leaky(sum + bias[c]);
}

// ---------------- GAT aggregation, H=1, fp16 rows, no max-pass ----------------
__global__ void gat_agg1h(const _Float16* __restrict__ h, const float* __restrict__ a_src,
                          const float* __restrict__ a_dst, const int* __restrict__ row_ptr,
                          const int* __restrict__ col, const float* __restrict__ bias,
                          float* __restrict__ outp, int N) {
    int i = blockIdx.x;
    int w = threadIdx.x >> 6, lane = threadIdx.x & 63;
    int start = row_ptr[i], end = row_ptr[i + 1];
    float ad = a_dst[i];

    float ssum = 0.0f;
    for (int j = start + lane; j < end; j += 64)
        ssum += __expf(leaky(a_src[col[j]] + ad));
    ssum = wave_sum(ssum);
    float inv = 1.0f / ssum;

    // 4 subgroups x 4 waves = 16 edges in flight; 16 lanes x half4 (8B) = 128B row
    int sub = lane >> 4;
    int c4 = (lane & 15) * 4;
    float4 acc = make_float4(0.f, 0.f, 0.f, 0.f);
    for (int j = start + w * 4 + sub; j < end; j += 16) {
        int s = col[j];
        float alpha = __expf(leaky(a_src[s] + ad)) * inv;
        half4v v = *(const half4v*)(h + (size_t)s * 64 + c4);
        acc.x += alpha * (float)v[0]; acc.y += alpha * (float)v[1];
        acc.z += alpha * (float)v[2]; acc.w += alpha * (float)v[3];
    }
    #pragma unroll
    for (int o = 16; o <= 32; o <<= 1) {
        acc.x += __shfl_xor(acc.x, o, 64);
        acc.y += __shfl_xor(acc.y, o, 64);
        acc.z += __shfl_xor(acc.z, o, 64);
        acc.w += __shfl_xor(acc.w, o, 64);
    }
    __shared__ float accs[4][64];
    if (lane < 16) *(float4*)&accs[w][c4] = acc;
    __syncthreads();
    if (threadIdx.x < 64) {
        int c = threadIdx.x;
        float sum = accs[0][c] + accs[1][c] + accs[2][c] + accs[3][c];
        outp[(size_t)i * 64 + c] = leaky(sum + bias[c]);
    }
}

// ---------------- leaky'd o2 -> LayerNorm -> + residual(lin) -> hres fp16 ----------------
__global__ void ln_res(const float* __restrict__ o2, const float* __restrict__ lin,
                       _Float16* __restrict__ hresh,
                       const float* __restrict__ gamma, const float* __restrict__ beta, int N) {
    int wave = threadIdx.x >> 6, lane = threadIdx.x & 63;
    int i = blockIdx.x * (blockDim.x >> 6) + wave;
    if (i >= N) return;
    float x = o2[(size_t)i * 64 + lane];
    float mu = wave_sum(x) * (1.0f / 64.0f);
    float d = x - mu;
    float var = wave_sum(d * d) * (1.0f / 64.0f);
    float xn = d * rsqrtf(var + LN_EPS) * gamma[lane] + beta[lane];
    float v = lin[(size_t)i * 64 + lane] + xn;
    hresh[(size_t)i * 64 + lane] = (_Float16)v;
}

// ---------------- GRU gates + FC head ----------------
__global__ void gru_fc(const float* __restrict__ gi, const float* __restrict__ b_hh,
                       const float* __restrict__ fc_w, const float* __restrict__ fc_b,
                       float* __restrict__ outp, int N) {
    int wave = threadIdx.x >> 6, lane = threadIdx.x & 63;
    int i = blockIdx.x * (blockDim.x >> 6) + wave;
    if (i >= N) return;
    const float* g = gi + (size_t)i * 192;
    float i_r = g[lane], i_z = g[64 + lane], i_n = g[128 + lane];
    float r = 1.0f / (1.0f + __expf(-(i_r + b_hh[lane])));
    float z = 1.0f / (1.0f + __expf(-(i_z + b_hh[64 + lane])));
    float ng = tanhf(i_n + r * b_hh[128 + lane]);
    float hy = (1.0f - z) * ng;
    #pragma unroll
    for (int k = 0; k < 3; ++k) {
        float s = wave_sum(hy * fc_w[k * 64 + lane]);
        if (lane == 0) outp[(size_t)i * 3 + k] = s + fc_b[k];
    }
}

extern "C" void kernel_launch(void* const* d_in, const int* in_sizes, int n_in,
                              void* d_out, int out_size, void* d_ws, size_t ws_size,
                              hipStream_t stream) {
    const float* x        = (const float*)d_in[0];
    const int*   ei       = (const int*)d_in[1];
    const float* W1       = (const float*)d_in[2];
    const float* att_src1 = (const float*)d_in[3];
    const float* att_dst1 = (const float*)d_in[4];
    const float* b1       = (const float*)d_in[5];
    const float* W2       = (const float*)d_in[6];
    const float* att_src2 = (const float*)d_in[7];
    const float* att_dst2 = (const float*)d_in[8];
    const float* b2       = (const float*)d_in[9];
    const float* lin_w    = (const float*)d_in[10];
    const float* lin_b    = (const float*)d_in[11];
    const float* gamma    = (const float*)d_in[12];
    const float* beta     = (const float*)d_in[13];
    const float* w_ih     = (const float*)d_in[14];
    // d_in[15] = w_hh (unused: h0 == 0)
    const float* b_ih     = (const float*)d_in[16];
    const float* b_hh     = (const float*)d_in[17];
    const float* fc_w     = (const float*)d_in[18];
    const float* fc_b     = (const float*)d_in[19];
    float* out = (float*)d_out;

    const int N = N_NODES, E = N_EDGES;
    const int Etot = E + N;
    char* ws = (char*)d_ws;

    size_t off = 0;
    auto alloc = [&](size_t bytes) {
        size_t o = off;
        off = (off + bytes + 255) & ~(size_t)255;
        return o;
    };
    int*      row_ptr = (int*)(ws + alloc((size_t)(N + 1) * 4));
    int*      col     = (int*)(ws + alloc((size_t)Etot * 4));
    int*      deg     = (int*)(ws + alloc((size_t)N * 4));
    int*      fill    = (int*)(ws + alloc((size_t)N * 4));
    float*    a_src1b = (float*)(ws + alloc((size_t)N * HEADS * 4));
    float*    a_dst1b = (float*)(ws + alloc((size_t)N * HEADS * 4));
    float*    a_src2b = (float*)(ws + alloc((size_t)N * 4));
    float*    a_dst2b = (float*)(ws + alloc((size_t)N * 4));
    _Float16* W1h     = (_Float16*)(ws + alloc((size_t)256 * 256 * 2));
    _Float16* W2h     = (_Float16*)(ws + alloc((size_t)64 * 256 * 2));
    _Float16* lin_wh  = (_Float16*)(ws + alloc((size_t)64 * 256 * 2));
    _Float16* w_ihh   = (_Float16*)(ws + alloc((size_t)192 * 64 * 2));
    // big region (64MB): xh@0 (25.6M), h1h@25.6M (25.6M), lin@51.2M (12.8M).
    // gi (fp32, 38.4M) aliases [0, 38.4M) AFTER xh & h1h are dead; lin untouched.
    char* big = ws + alloc((size_t)64000000);
    _Float16* xh   = (_Float16*)big;
    _Float16* h1h  = (_Float16*)(big + 25600000);
    float*    lin  = (float*)(big + 51200000);
    float*    gi   = (float*)big;
    // region r3 (25.6M): o1h (fp16 [N,256]); after gemm2 consumes it, reused as o2 (fp32 [N,64])
    char* r3 = ws + alloc((size_t)25600000);
    _Float16* o1h = (_Float16*)r3;
    float*    o2  = (float*)r3;
    // region r4 (6.4M): h2h (fp16 [N,64]); after gat_agg1h, reused as hresh (fp16 [N,64])
    char* r4 = ws + alloc((size_t)6400000);
    _Float16* h2h   = (_Float16*)r4;
    _Float16* hresh = (_Float16*)r4;

    hipMemsetAsync(deg, 0, (size_t)N * 4, stream);
    hipMemsetAsync(fill, 0, (size_t)N * 4, stream);

    // ---- CSR build ----
    count_kernel<<<(Etot + 255) / 256, 256, 0, stream>>>(ei + E, deg, E, Etot);
    scan_kernel<<<1, 1024, 0, stream>>>(deg, row_ptr, N);
    scatter_kernel<<<(Etot + 255) / 256, 256, 0, stream>>>(ei, ei + E, row_ptr, fill, col, E, Etot);

    // ---- fp16 conversions (one kernel, 5 ranges) ----
    {
        CvtJob j0{x, xh, N * F_IN};
        CvtJob j1{W1, W1h, 256 * 256};
        CvtJob j2{W2, W2h, 64 * 256};
        CvtJob j3{lin_w, lin_wh, 64 * 256};
        CvtJob j4{w_ih, w_ihh, 192 * 64};
        int total4 = (j0.len + j1.len + j2.len + j3.len + j4.len) / 4;
        cvt_f16_multi<<<(total4 + 255) / 256, 256, 0, stream>>>(j0, j1, j2, j3, j4);
    }

    const int gmBlocks = (N + 63) / 64;   // 782

    // ---- GAT layer 1 (att coefs fused into GEMM epilogue) ----
    gemm_mfma<16, 4><<<gmBlocks, 256, 0, stream>>>(xh, W1h, nullptr, h1h,
        att_src1, att_dst1, a_src1b, a_dst1b, N, 256, 1, 0);
    gat_agg4<<<N, 256, 0, stream>>>(h1h, a_src1b, a_dst1b, row_ptr, col, b1, o1h, N);

    // ---- residual projection: lin = x @ lin_w^T + lin_b (fp32 out) ----
    gemm_mfma<4, 0><<<gmBlocks, 256, 0, stream>>>(xh, lin_wh, lin_b, lin,
        nullptr, nullptr, nullptr, nullptr, N, 256, 0, 1);

    // ---- GAT layer 2 (att coefs fused) ----
    gemm_mfma<4, 1><<<gmBlocks, 256, 0, stream>>>(o1h, W2h, nullptr, h2h,
        att_src2, att_dst2, a_src2b, a_dst2b, N, 256, 1, 0);
    gat_agg1h<<<N, 256, 0, stream>>>(h2h, a_src2b, a_dst2b, row_ptr, col, b2, o2, N);

    // ---- LayerNorm + residual -> hres fp16 ----
    ln_res<<<(N + 3) / 4, 256, 0, stream>>>(o2, lin, hresh, gamma, beta, N);

    // ---- GRU input GEMM: gi = hres @ w_ih^T + b_ih (fp32 out) ----
    gemm_mfma<12, 0><<<gmBlocks, 256, 0, stream>>>(hresh, w_ihh, b_ih, gi,
        nullptr, nullptr, nullptr, nullptr, N, 64, 0, 1);

    // ---- GRU gates + FC head ----
    gru_fc<<<(N + 3) / 4, 256, 0, stream>>>(gi, b_hh, fc_w, fc_b, out, N);
}

// Round 6
// 525.845 us; speedup vs baseline: 1.6004x; 1.2009x over previous
//
#include <hip/hip_runtime.h>
#include <hip/hip_bf16.h>

#define N_NODES 50000
#define N_EDGES 800000
#define F_IN 256
#define HID 64
#define HEADS 4
#define NEG 0.2f
#define LN_EPS 1e-5f

typedef _Float16 half8 __attribute__((ext_vector_type(8)));
typedef _Float16 half4v __attribute__((ext_vector_type(4)));
typedef float floatx4 __attribute__((ext_vector_type(4)));

__device__ __forceinline__ float wave_sum(float v) {
    #pragma unroll
    for (int o = 32; o > 0; o >>= 1) v += __shfl_xor(v, o, 64);
    return v;
}
__device__ __forceinline__ int wave_sum_i(int v) {
    #pragma unroll
    for (int o = 32; o > 0; o >>= 1) v += __shfl_xor(v, o, 64);
    return v;
}
__device__ __forceinline__ float leaky(float x) { return x > 0.0f ? x : NEG * x; }

// ---------------- CSR build ----------------
__global__ void count_kernel(const int* __restrict__ dst, int* __restrict__ deg,
                             int E, int Etot) {
    int e = blockIdx.x * blockDim.x + threadIdx.x;
    if (e >= Etot) return;
    int d = (e < E) ? dst[e] : (e - E);   // tail = self loops
    atomicAdd(&deg[d], 1);
}

// hierarchical scan: part-sums (196 blocks) -> top exclusive scan (1 block) -> final
__global__ void scan_part(const int* __restrict__ deg, int* __restrict__ bsum, int N) {
    int tid = threadIdx.x;
    int i = blockIdx.x * 256 + tid;
    int v = (i < N) ? deg[i] : 0;
    int s = wave_sum_i(v);
    __shared__ int ws4[4];
    if ((tid & 63) == 0) ws4[tid >> 6] = s;
    __syncthreads();
    if (tid == 0) bsum[blockIdx.x] = ws4[0] + ws4[1] + ws4[2] + ws4[3];
}

__global__ void scan_top(int* __restrict__ bsum, int nb) {   // in-place exclusive
    __shared__ int sh[256];
    int t = threadIdx.x;
    int v = (t < nb) ? bsum[t] : 0;
    sh[t] = v;
    __syncthreads();
    for (int o = 1; o < 256; o <<= 1) {
        int u = (t >= o) ? sh[t - o] : 0;
        __syncthreads();
        sh[t] += u;
        __syncthreads();
    }
    if (t < nb) bsum[t] = sh[t] - v;    // exclusive
}

__global__ void scan_final(const int* __restrict__ deg, const int* __restrict__ bsum,
                           int* __restrict__ row_ptr, int N) {
    __shared__ int sh[256];
    int t = threadIdx.x;
    int i = blockIdx.x * 256 + t;
    int v = (i < N) ? deg[i] : 0;
    sh[t] = v;
    __syncthreads();
    for (int o = 1; o < 256; o <<= 1) {
        int u = (t >= o) ? sh[t - o] : 0;
        __syncthreads();
        sh[t] += u;
        __syncthreads();
    }
    if (i < N) row_ptr[i + 1] = bsum[blockIdx.x] + sh[t];   // inclusive prefix
    if (i == 0) row_ptr[0] = 0;
}

__global__ void scatter_kernel(const int* __restrict__ src, const int* __restrict__ dst,
                               const int* __restrict__ row_ptr, int* __restrict__ fill,
                               int* __restrict__ col, int E, int Etot) {
    int e = blockIdx.x * blockDim.x + threadIdx.x;
    if (e >= Etot) return;
    int s, d;
    if (e < E) { s = src[e]; d = dst[e]; }
    else       { s = d = e - E; }
    int pos = atomicAdd(&fill[d], 1);
    col[row_ptr[d] + pos] = s;
}

// ---------------- merged fp32 -> fp16 conversion over 5 ranges ----------------
struct CvtJob { const float* src; _Float16* dst; int len; };
__global__ void cvt_f16_multi(CvtJob j0, CvtJob j1, CvtJob j2, CvtJob j3, CvtJob j4) {
    int idx = (blockIdx.x * blockDim.x + threadIdx.x) * 4;
    const float* s; _Float16* d; int rel = idx;
    if      (rel < j0.len) { s = j0.src; d = j0.dst; }
    else if ((rel -= j0.len) < j1.len) { s = j1.src; d = j1.dst; }
    else if ((rel -= j1.len) < j2.len) { s = j2.src; d = j2.dst; }
    else if ((rel -= j2.len) < j3.len) { s = j3.src; d = j3.dst; }
    else if ((rel -= j3.len) < j4.len) { s = j4.src; d = j4.dst; }
    else return;
    float4 v = *(const float4*)(s + rel);
    half4v h;
    h[0] = (_Float16)v.x; h[1] = (_Float16)v.y;
    h[2] = (_Float16)v.z; h[3] = (_Float16)v.w;
    *(half4v*)(d + rel) = h;
}

// ---------------- fp16 MFMA GEMM + optional fused attention-coefficient epilogue ----------
template<int NT, int H>
__global__ void gemm_mfma(const _Float16* __restrict__ A, const _Float16* __restrict__ B,
                          const float* __restrict__ bias, void* __restrict__ Cout,
                          const float* __restrict__ att_s, const float* __restrict__ att_d,
                          float* __restrict__ a_srcO, float* __restrict__ a_dstO,
                          int M, int K, int out_f16, int add_bias) {
    int w = threadIdx.x >> 6, lane = threadIdx.x & 63;
    int m_base = blockIdx.x * 64 + w * 16;
    if (m_base >= M) return;                 // M % 16 == 0 -> uniform per wave
    int r = lane & 15, q = lane >> 4;
    const _Float16* ap = A + (size_t)(m_base + r) * K + q * 8;
    const _Float16* bp = B + (size_t)r * K + q * 8;
    floatx4 acc[NT];
    #pragma unroll
    for (int t = 0; t < NT; ++t) acc[t] = (floatx4){0.f, 0.f, 0.f, 0.f};
    for (int k0 = 0; k0 < K; k0 += 32) {
        half8 a = *(const half8*)(ap + k0);
        #pragma unroll
        for (int t = 0; t < NT; ++t) {
            half8 b = *(const half8*)(bp + (size_t)t * 16 * K + k0);
            acc[t] = __builtin_amdgcn_mfma_f32_16x16x32_f16(a, b, acc[t], 0, 0, 0);
        }
    }
    const int Nc = NT * 16;
    #pragma unroll
    for (int t = 0; t < NT; ++t) {
        int cc = t * 16 + r;
        float bv = add_bias ? bias[cc] : 0.0f;
        #pragma unroll
        for (int rr = 0; rr < 4; ++rr) {
            int gm = m_base + q * 4 + rr;
            float v = acc[t][rr] + bv;
            if (out_f16) ((_Float16*)Cout)[(size_t)gm * Nc + cc] = (_Float16)v;
            else         ((float*)Cout)[(size_t)gm * Nc + cc] = v;
        }
    }
    if constexpr (H > 0) {
        float ps[H][4], pd[H][4];
        #pragma unroll
        for (int h = 0; h < H; ++h) {
            #pragma unroll
            for (int rr = 0; rr < 4; ++rr) { ps[h][rr] = 0.f; pd[h][rr] = 0.f; }
            #pragma unroll
            for (int tt = 0; tt < 4; ++tt) {
                int t = h * 4 + tt;
                float as = att_s[t * 16 + r];
                float ad = att_d[t * 16 + r];
                #pragma unroll
                for (int rr = 0; rr < 4; ++rr) {
                    ps[h][rr] += acc[t][rr] * as;
                    pd[h][rr] += acc[t][rr] * ad;
                }
            }
        }
        #pragma unroll
        for (int m = 1; m < 16; m <<= 1) {
            #pragma unroll
            for (int h = 0; h < H; ++h)
                #pragma unroll
                for (int rr = 0; rr < 4; ++rr) {
                    ps[h][rr] += __shfl_xor(ps[h][rr], m, 64);
                    pd[h][rr] += __shfl_xor(pd[h][rr], m, 64);
                }
        }
        if (r == 0) {
            #pragma unroll
            for (int rr = 0; rr < 4; ++rr) {
                int gm = m_base + q * 4 + rr;
                #pragma unroll
                for (int h = 0; h < H; ++h) {
                    a_srcO[gm * H + h] = ps[h][rr];
                    a_dstO[gm * H + h] = pd[h][rr];
                }
            }
        }
    }
}

// ---------------- GAT aggregation, H=4: LDS-cached alphas (deg<=64 fast path) -------------
__global__ void gat_agg4(const _Float16* __restrict__ h, const float* __restrict__ a_src,
                         const float* __restrict__ a_dst, const int* __restrict__ row_ptr,
                         const int* __restrict__ col, const float* __restrict__ bias,
                         _Float16* __restrict__ outp, int N) {
    int i = blockIdx.x;
    int w = threadIdx.x >> 6, lane = threadIdx.x & 63;
    int start = row_ptr[i], end = row_ptr[i + 1];
    int deg = end - start;

    __shared__ float invs[4];
    __shared__ float alph[4][64];
    __shared__ int   scol[64];
    __shared__ float accs[4][256];

    float ad = a_dst[i * 4 + w];
    float ssum = 0.0f;
    if (deg <= 64) {
        int s = 0; float e = 0.0f;
        if (lane < deg) {
            s = col[start + lane];
            e = __expf(leaky(a_src[s * 4 + w] + ad));
        }
        if (w == 0) scol[lane] = s;
        alph[w][lane] = e;
        ssum = wave_sum(e);
    } else {
        for (int j = start + lane; j < end; j += 64)
            ssum += __expf(leaky(a_src[col[j] * 4 + w] + ad));
        ssum = wave_sum(ssum);
    }
    if (lane == 0) invs[w] = 1.0f / ssum;
    __syncthreads();

    int hh = lane >> 4;
    float ih = invs[hh];
    float4 acc = make_float4(0.f, 0.f, 0.f, 0.f);
    if (deg <= 64) {
        int j = w;
        for (; j + 12 < deg; j += 16) {
            int s0 = scol[j], s1 = scol[j + 4], s2 = scol[j + 8], s3 = scol[j + 12];
            float a0 = alph[hh][j] * ih,      a1 = alph[hh][j + 4] * ih;
            float a2 = alph[hh][j + 8] * ih,  a3 = alph[hh][j + 12] * ih;
            half4v v0 = *(const half4v*)(h + (size_t)s0 * 256 + lane * 4);
            half4v v1 = *(const half4v*)(h + (size_t)s1 * 256 + lane * 4);
            half4v v2 = *(const half4v*)(h + (size_t)s2 * 256 + lane * 4);
            half4v v3 = *(const half4v*)(h + (size_t)s3 * 256 + lane * 4);
            acc.x += a0 * (float)v0[0] + a1 * (float)v1[0] + a2 * (float)v2[0] + a3 * (float)v3[0];
            acc.y += a0 * (float)v0[1] + a1 * (float)v1[1] + a2 * (float)v2[1] + a3 * (float)v3[1];
            acc.z += a0 * (float)v0[2] + a1 * (float)v1[2] + a2 * (float)v2[2] + a3 * (float)v3[2];
            acc.w += a0 * (float)v0[3] + a1 * (float)v1[3] + a2 * (float)v2[3] + a3 * (float)v3[3];
        }
        for (; j < deg; j += 4) {
            int s = scol[j];
            float a0 = alph[hh][j] * ih;
            half4v v = *(const half4v*)(h + (size_t)s * 256 + lane * 4);
            acc.x += a0 * (float)v[0]; acc.y += a0 * (float)v[1];
            acc.z += a0 * (float)v[2]; acc.w += a0 * (float)v[3];
        }
    } else {
        float adh = a_dst[i * 4 + hh];
        for (int j = start + w; j < end; j += 4) {
            int s = col[j];
            float alpha = __expf(leaky(a_src[s * 4 + hh] + adh)) * ih;
            half4v v = *(const half4v*)(h + (size_t)s * 256 + lane * 4);
            acc.x += alpha * (float)v[0]; acc.y += alpha * (float)v[1];
            acc.z += alpha * (float)v[2]; acc.w += alpha * (float)v[3];
        }
    }
    *(float4*)&accs[w][lane * 4] = acc;
    __syncthreads();

    int c = threadIdx.x;
    float sum = accs[0][c] + accs[1][c] + accs[2][c] + accs[3][c];
    outp[(size_t)i * 256 + c] = (_Float16)leaky(sum + bias[c]);
}

// ---------------- GAT aggregation, H=1: LDS-cached alphas + 2-deep batching --------------
__global__ void gat_agg1h(const _Float16* __restrict__ h, const float* __restrict__ a_src,
                          const float* __restrict__ a_dst, const int* __restrict__ row_ptr,
                          const int* __restrict__ col, const float* __restrict__ bias,
                          float* __restrict__ outp, int N) {
    int i = blockIdx.x;
    int w = threadIdx.x >> 6, lane = threadIdx.x & 63;
    int start = row_ptr[i], end = row_ptr[i + 1];
    int deg = end - start;
    float ad = a_dst[i];

    __shared__ float alph[64];
    __shared__ int   scol[64];
    __shared__ float accs[4][64];

    float ssum = 0.0f;
    if (deg <= 64) {
        int s = 0; float e = 0.0f;
        if (lane < deg) {
            s = col[start + lane];
            e = __expf(leaky(a_src[s] + ad));
        }
        if (w == 0) { scol[lane] = s; alph[lane] = e; }
        ssum = wave_sum(e);
    } else {
        for (int j = start + lane; j < end; j += 64)
            ssum += __expf(leaky(a_src[col[j]] + ad));
        ssum = wave_sum(ssum);
    }
    float inv = 1.0f / ssum;
    __syncthreads();

    int sub = lane >> 4;
    int c4 = (lane & 15) * 4;
    int es = w * 4 + sub;                  // 0..15: this subgroup's edge offset
    float4 acc = make_float4(0.f, 0.f, 0.f, 0.f);
    if (deg <= 64) {
        int j = es;
        for (; j + 16 < deg; j += 32) {
            int s0 = scol[j], s1 = scol[j + 16];
            float a0 = alph[j] * inv, a1 = alph[j + 16] * inv;
            half4v v0 = *(const half4v*)(h + (size_t)s0 * 64 + c4);
            half4v v1 = *(const half4v*)(h + (size_t)s1 * 64 + c4);
            acc.x += a0 * (float)v0[0] + a1 * (float)v1[0];
            acc.y += a0 * (float)v0[1] + a1 * (float)v1[1];
            acc.z += a0 * (float)v0[2] + a1 * (float)v1[2];
            acc.w += a0 * (float)v0[3] + a1 * (float)v1[3];
        }
        for (; j < deg; j += 16) {
            int s = scol[j];
            float a0 = alph[j] * inv;
            half4v v = *(const half4v*)(h + (size_t)s * 64 + c4);
            acc.x += a0 * (float)v[0]; acc.y += a0 * (float)v[1];
            acc.z += a0 * (float)v[2]; acc.w += a0 * (float)v[3];
        }
    } else {
        for (int j = start + es; j < end; j += 16) {
            int s = col[j];
            float alpha = __expf(leaky(a_src[s] + ad)) * inv;
            half4v v = *(const half4v*)(h + (size_t)s * 64 + c4);
            acc.x += alpha * (float)v[0]; acc.y += alpha * (float)v[1];
            acc.z += alpha * (float)v[2]; acc.w += alpha * (float)v[3];
        }
    }
    #pragma unroll
    for (int o = 16; o <= 32; o <<= 1) {
        acc.x += __shfl_xor(acc.x, o, 64);
        acc.y += __shfl_xor(acc.y, o, 64);
        acc.z += __shfl_xor(acc.z, o, 64);
        acc.w += __shfl_xor(acc.w, o, 64);
    }
    if (lane < 16) *(float4*)&accs[w][c4] = acc;
    __syncthreads();
    if (threadIdx.x < 64) {
        int c = threadIdx.x;
        float sum = accs[0][c] + accs[1][c] + accs[2][c] + accs[3][c];
        outp[(size_t)i * 64 + c] = leaky(sum + bias[c]);
    }
}

// ---------------- leaky'd o2 -> LayerNorm -> + residual(lin) -> hres fp16 ----------------
__global__ void ln_res(const float* __restrict__ o2, const float* __restrict__ lin,
                       _Float16* __restrict__ hresh,
                       const float* __restrict__ gamma, const float* __restrict__ beta, int N) {
    int wave = threadIdx.x >> 6, lane = threadIdx.x & 63;
    int i = blockIdx.x * (blockDim.x >> 6) + wave;
    if (i >= N) return;
    float x = o2[(size_t)i * 64 + lane];
    float mu = wave_sum(x) * (1.0f / 64.0f);
    float d = x - mu;
    float var = wave_sum(d * d) * (1.0f / 64.0f);
    float xn = d * rsqrtf(var + LN_EPS) * gamma[lane] + beta[lane];
    float v = lin[(size_t)i * 64 + lane] + xn;
    hresh[(size_t)i * 64 + lane] = (_Float16)v;
}

// ---------------- GRU gates + FC head (gi fp16) ----------------
__global__ void gru_fc(const _Float16* __restrict__ gi, const float* __restrict__ b_hh,
                       const float* __restrict__ fc_w, const float* __restrict__ fc_b,
                       float* __restrict__ outp, int N) {
    int wave = threadIdx.x >> 6, lane = threadIdx.x & 63;
    int i = blockIdx.x * (blockDim.x >> 6) + wave;
    if (i >= N) return;
    const _Float16* g = gi + (size_t)i * 192;
    float i_r = (float)g[lane], i_z = (float)g[64 + lane], i_n = (float)g[128 + lane];
    float r = 1.0f / (1.0f + __expf(-(i_r + b_hh[lane])));
    float z = 1.0f / (1.0f + __expf(-(i_z + b_hh[64 + lane])));
    float ng = tanhf(i_n + r * b_hh[128 + lane]);
    float hy = (1.0f - z) * ng;
    #pragma unroll
    for (int k = 0; k < 3; ++k) {
        float s = wave_sum(hy * fc_w[k * 64 + lane]);
        if (lane == 0) outp[(size_t)i * 3 + k] = s + fc_b[k];
    }
}

extern "C" void kernel_launch(void* const* d_in, const int* in_sizes, int n_in,
                              void* d_out, int out_size, void* d_ws, size_t ws_size,
                              hipStream_t stream) {
    const float* x        = (const float*)d_in[0];
    const int*   ei       = (const int*)d_in[1];
    const float* W1       = (const float*)d_in[2];
    const float* att_src1 = (const float*)d_in[3];
    const float* att_dst1 = (const float*)d_in[4];
    const float* b1       = (const float*)d_in[5];
    const float* W2       = (const float*)d_in[6];
    const float* att_src2 = (const float*)d_in[7];
    const float* att_dst2 = (const float*)d_in[8];
    const float* b2       = (const float*)d_in[9];
    const float* lin_w    = (const float*)d_in[10];
    const float* lin_b    = (const float*)d_in[11];
    const float* gamma    = (const float*)d_in[12];
    const float* beta     = (const float*)d_in[13];
    const float* w_ih     = (const float*)d_in[14];
    // d_in[15] = w_hh (unused: h0 == 0)
    const float* b_ih     = (const float*)d_in[16];
    const float* b_hh     = (const float*)d_in[17];
    const float* fc_w     = (const float*)d_in[18];
    const float* fc_b     = (const float*)d_in[19];
    float* out = (float*)d_out;

    const int N = N_NODES, E = N_EDGES;
    const int Etot = E + N;
    const int nb = (N + 255) / 256;       // 196 scan blocks
    char* ws = (char*)d_ws;

    size_t off = 0;
    auto alloc = [&](size_t bytes) {
        size_t o = off;
        off = (off + bytes + 255) & ~(size_t)255;
        return o;
    };
    int*      row_ptr = (int*)(ws + alloc((size_t)(N + 1) * 4));
    int*      col     = (int*)(ws + alloc((size_t)Etot * 4));
    int*      deg     = (int*)(ws + alloc((size_t)N * 4));
    int*      fill    = (int*)(ws + alloc((size_t)N * 4));
    int*      bsum    = (int*)(ws + alloc((size_t)nb * 4));
    float*    a_src1b = (float*)(ws + alloc((size_t)N * HEADS * 4));
    float*    a_dst1b = (float*)(ws + alloc((size_t)N * HEADS * 4));
    float*    a_src2b = (float*)(ws + alloc((size_t)N * 4));
    float*    a_dst2b = (float*)(ws + alloc((size_t)N * 4));
    _Float16* W1h     = (_Float16*)(ws + alloc((size_t)256 * 256 * 2));
    _Float16* W2h     = (_Float16*)(ws + alloc((size_t)64 * 256 * 2));
    _Float16* lin_wh  = (_Float16*)(ws + alloc((size_t)64 * 256 * 2));
    _Float16* w_ihh   = (_Float16*)(ws + alloc((size_t)192 * 64 * 2));
    // big region (64MB): xh@0 (25.6M), h1h@25.6M (25.6M), lin@51.2M (12.8M).
    // gi (fp16, 19.2M) aliases [0, 19.2M) AFTER xh is dead; h1h/lin untouched.
    char* big = ws + alloc((size_t)64000000);
    _Float16* xh   = (_Float16*)big;
    _Float16* h1h  = (_Float16*)(big + 25600000);
    float*    lin  = (float*)(big + 51200000);
    _Float16* gi   = (_Float16*)big;
    // region r3 (25.6M): o1h (fp16 [N,256]); after gemm2 consumes it, reused as o2 (fp32 [N,64])
    char* r3 = ws + alloc((size_t)25600000);
    _Float16* o1h = (_Float16*)r3;
    float*    o2  = (float*)r3;
    // region r4 (6.4M): h2h (fp16 [N,64]); after gat_agg1h, reused as hresh (fp16 [N,64])
    char* r4 = ws + alloc((size_t)6400000);
    _Float16* h2h   = (_Float16*)r4;
    _Float16* hresh = (_Float16*)r4;

    hipMemsetAsync(deg, 0, (size_t)N * 4, stream);
    hipMemsetAsync(fill, 0, (size_t)N * 4, stream);

    // ---- CSR build ----
    count_kernel<<<(Etot + 255) / 256, 256, 0, stream>>>(ei + E, deg, E, Etot);
    scan_part<<<nb, 256, 0, stream>>>(deg, bsum, N);
    scan_top<<<1, 256, 0, stream>>>(bsum, nb);
    scan_final<<<nb, 256, 0, stream>>>(deg, bsum, row_ptr, N);
    scatter_kernel<<<(Etot + 255) / 256, 256, 0, stream>>>(ei, ei + E, row_ptr, fill, col, E, Etot);

    // ---- fp16 conversions (one kernel, 5 ranges) ----
    {
        CvtJob j0{x, xh, N * F_IN};
        CvtJob j1{W1, W1h, 256 * 256};
        CvtJob j2{W2, W2h, 64 * 256};
        CvtJob j3{lin_w, lin_wh, 64 * 256};
        CvtJob j4{w_ih, w_ihh, 192 * 64};
        int total4 = (j0.len + j1.len + j2.len + j3.len + j4.len) / 4;
        cvt_f16_multi<<<(total4 + 255) / 256, 256, 0, stream>>>(j0, j1, j2, j3, j4);
    }

    const int gmBlocks = (N + 63) / 64;   // 782

    // ---- GAT layer 1 (att coefs fused into GEMM epilogue) ----
    gemm_mfma<16, 4><<<gmBlocks, 256, 0, stream>>>(xh, W1h, nullptr, h1h,
        att_src1, att_dst1, a_src1b, a_dst1b, N, 256, 1, 0);
    gat_agg4<<<N, 256, 0, stream>>>(h1h, a_src1b, a_dst1b, row_ptr, col, b1, o1h, N);

    // ---- residual projection: lin = x @ lin_w^T + lin_b (fp32 out) ----
    gemm_mfma<4, 0><<<gmBlocks, 256, 0, stream>>>(xh, lin_wh, lin_b, lin,
        nullptr, nullptr, nullptr, nullptr, N, 256, 0, 1);

    // ---- GAT layer 2 (att coefs fused) ----
    gemm_mfma<4, 1><<<gmBlocks, 256, 0, stream>>>(o1h, W2h, nullptr, h2h,
        att_src2, att_dst2, a_src2b, a_dst2b, N, 256, 1, 0);
    gat_agg1h<<<N, 256, 0, stream>>>(h2h, a_src2b, a_dst2b, row_ptr, col, b2, o2, N);

    // ---- LayerNorm + residual -> hres fp16 ----
    ln_res<<<(N + 3) / 4, 256, 0, stream>>>(o2, lin, hresh, gamma, beta, N);

    // ---- GRU input GEMM: gi = hres @ w_ih^T + b_ih (fp16 out) ----
    gemm_mfma<12, 0><<<gmBlocks, 256, 0, stream>>>(hresh, w_ihh, b_ih, gi,
        nullptr, nullptr, nullptr, nullptr, N, 64, 1, 1);

    // ---- GRU gates + FC head ----
    gru_fc<<<(N + 3) / 4, 256, 0, stream>>>(gi, b_hh, fc_w, fc_b, out, N);
}